// Round 1
// baseline (542.568 us; speedup 1.0000x reference)
//
#include <hip/hip_runtime.h>
#include <math.h>

#define N_NODES 50000
#define N_EDGES 800000
#define N_QE    100000
#define D       128

// ---- workspace layout (bytes) ----
static const size_t O_CNT = 0;                        // int[N]
static const size_t O_OFF = 256u * 1024;              // int[N+1]
static const size_t O_CUR = 512u * 1024;              // int[N]
static const size_t O_BS  = 768u * 1024;              // int[256] block sums
static const size_t O_SRC = 1024u * 1024;             // int[E] (3.2 MB)
static const size_t O_A   = 8u << 20;                 // float[N*D] 25.6 MB
static const size_t O_B   = O_A + 25600000u;          // float[N*D] 25.6 MB

// ---- CSR build ----
__global__ void k_count(const int* __restrict__ dst, int* __restrict__ cnt) {
    int e = blockIdx.x * 256 + threadIdx.x;
    if (e < N_EDGES) atomicAdd(&cnt[dst[e]], 1);
}

__global__ __launch_bounds__(256)
void k_scan1(const int* __restrict__ cnt, int* __restrict__ off,
             int* __restrict__ bsum) {
    __shared__ int sh[256];
    const int t = threadIdx.x;
    const int i = blockIdx.x * 256 + t;
    int v = (i < N_NODES) ? cnt[i] : 0;
    sh[t] = v;
    __syncthreads();
    #pragma unroll
    for (int o = 1; o < 256; o <<= 1) {
        int u = (t >= o) ? sh[t - o] : 0;
        __syncthreads();
        sh[t] += u;
        __syncthreads();
    }
    if (i < N_NODES) off[i] = sh[t] - v;
    if (t == 255) bsum[blockIdx.x] = sh[255];
}

__global__ __launch_bounds__(256)
void k_scan2(int* __restrict__ bsum, int nblk) {
    __shared__ int sh[256];
    const int t = threadIdx.x;
    int v = (t < nblk) ? bsum[t] : 0;
    sh[t] = v;
    __syncthreads();
    #pragma unroll
    for (int o = 1; o < 256; o <<= 1) {
        int u = (t >= o) ? sh[t - o] : 0;
        __syncthreads();
        sh[t] += u;
        __syncthreads();
    }
    if (t < nblk) bsum[t] = sh[t] - v;
}

__global__ __launch_bounds__(256)
void k_scan3(int* __restrict__ off, const int* __restrict__ bsum,
             int* __restrict__ cur) {
    const int i = blockIdx.x * 256 + threadIdx.x;
    if (i < N_NODES) {
        int o = off[i] + bsum[blockIdx.x];
        off[i] = o;
        cur[i] = o;
    }
    if (i == 0) off[N_NODES] = N_EDGES;
}

__global__ void k_scatter(const int* __restrict__ src, const int* __restrict__ dst,
                          int* __restrict__ cur, int* __restrict__ srcs) {
    int e = blockIdx.x * 256 + threadIdx.x;
    if (e < N_EDGES) {
        int p = atomicAdd(&cur[dst[e]], 1);
        srcs[p] = src[e];
    }
}

// ---- GEMM: Y[rows x 128] = X[rows x 128] @ W[128 x 128], fp32 ----
// 512 threads / 64-row tile, 32-k chunks. In-place safe (X==Y).
__global__ __launch_bounds__(512)
void k_gemm(const float* __restrict__ X, const float* __restrict__ W,
            float* __restrict__ Y, int rows)
{
    __shared__ float xs[64][36];
    __shared__ float ws[32 * 128];
    const int tid = threadIdx.x;
    const int tx = tid & 31;
    const int ty = tid >> 5;
    const int row0 = blockIdx.x * 64;
    float acc[4][4] = {};

    for (int kc = 0; kc < 4; ++kc) {
        const int kb = kc * 32;
        __syncthreads();
        {
            int r = tid >> 3, kq = tid & 7;
            int gr = row0 + r; if (gr >= rows) gr = rows - 1;
            float4 v = *(const float4*)(X + (size_t)gr * D + kb + kq * 4);
            *(float4*)&xs[r][kq * 4] = v;
        }
        #pragma unroll
        for (int it = 0; it < 2; ++it) {
            int f = it * 512 + tid;
            int k = f >> 5, cq = f & 31;
            *(float4*)&ws[k * 128 + cq * 4] =
                *(const float4*)(W + (size_t)(kb + k) * D + cq * 4);
        }
        __syncthreads();

        #pragma unroll 2
        for (int k4 = 0; k4 < 32; k4 += 4) {
            float4 wv[4];
            #pragma unroll
            for (int kk = 0; kk < 4; ++kk)
                wv[kk] = *(const float4*)&ws[(k4 + kk) * 128 + tx * 4];
            #pragma unroll
            for (int i = 0; i < 4; ++i) {
                float4 xv = *(const float4*)&xs[ty * 4 + i][k4];
                float xk[4] = {xv.x, xv.y, xv.z, xv.w};
                #pragma unroll
                for (int kk = 0; kk < 4; ++kk) {
                    acc[i][0] = fmaf(xk[kk], wv[kk].x, acc[i][0]);
                    acc[i][1] = fmaf(xk[kk], wv[kk].y, acc[i][1]);
                    acc[i][2] = fmaf(xk[kk], wv[kk].z, acc[i][2]);
                    acc[i][3] = fmaf(xk[kk], wv[kk].w, acc[i][3]);
                }
            }
        }
    }

    #pragma unroll
    for (int i = 0; i < 4; ++i) {
        int gr = row0 + ty * 4 + i;
        if (gr < rows)
            *(float4*)(Y + (size_t)gr * D + tx * 4) =
                make_float4(acc[i][0], acc[i][1], acc[i][2], acc[i][3]);
    }
}

// ---- CSR aggregation (fp32): ONE node per WAVE, scalar src ids ----
// off[n]/off[n+1] are wave-uniform -> readfirstlane forces SGPR; srcs[j+k]
// with uniform j and literal k compiles to s_load (batched dwordx8).
// Row address = SGPR base + lane*8: zero VALU per edge, no bpermute.
// 32-deep explicit load array => 32 outstanding 512B loads per wave
// (16 KB in flight/wave vs 8 KB in the old half-wave design).
template<bool RELU>
__global__ __launch_bounds__(256)
void k_agg(const float* __restrict__ Hin, const int* __restrict__ off,
           const int* __restrict__ srcs, const float* __restrict__ bias,
           float* __restrict__ Hout)
{
    const int lane = threadIdx.x & 63;
    const int wv   = threadIdx.x >> 6;        // 0..3
    const int n    = blockIdx.x * 4 + wv;     // one node per wave
    const int j0 = __builtin_amdgcn_readfirstlane(off[n]);
    const int j1 = __builtin_amdgcn_readfirstlane(off[n + 1]);

    float ax = 0.f, ay = 0.f;
    int j = j0;

    for (; j + 32 <= j1; j += 32) {
        float2 v[32];
        #pragma unroll
        for (int k = 0; k < 32; ++k) {
            int s = srcs[j + k];              // scalar load (uniform addr)
            v[k] = *((const float2*)(Hin + (size_t)s * D) + lane);
        }
        #pragma unroll
        for (int k = 0; k < 32; ++k) { ax += v[k].x; ay += v[k].y; }
    }
    for (; j + 8 <= j1; j += 8) {
        float2 v[8];
        #pragma unroll
        for (int k = 0; k < 8; ++k) {
            int s = srcs[j + k];
            v[k] = *((const float2*)(Hin + (size_t)s * D) + lane);
        }
        #pragma unroll
        for (int k = 0; k < 8; ++k) { ax += v[k].x; ay += v[k].y; }
    }
    for (; j < j1; ++j) {
        int s = srcs[j];
        float2 v = *((const float2*)(Hin + (size_t)s * D) + lane);
        ax += v.x; ay += v.y;
    }

    const float2 bb = ((const float2*)bias)[lane];
    float ox = ax + bb.x, oy = ay + bb.y;
    if (RELU) { ox = fmaxf(ox, 0.f); oy = fmaxf(oy, 0.f); }
    ((float2*)(Hout + (size_t)n * D))[lane] = make_float2(ox, oy);
}

// ---- fused link predictor, 512 threads / 64 edges per block ----
// Weight chunk shrunk 64x128 -> 32x128 floats: LDS 66560 -> 50176 B,
// 2 -> 3 blocks/CU (16 -> 24 waves) to lift occupancy.
__global__ __launch_bounds__(512)
void k_pred(const float* __restrict__ emb, const int* __restrict__ te,
            const float* __restrict__ P1, const float* __restrict__ pb1,
            const float* __restrict__ P2, const float* __restrict__ pb2,
            const float* __restrict__ P3, const float* __restrict__ pb3,
            float* __restrict__ out)
{
    __shared__ float xs[64][132];     // full 128-k activations, +4 pad
    __shared__ float ws[32 * 128];    // one 32-k weight chunk (16 KB)
    const int tid = threadIdx.x;      // 0..511
    const int tx = tid & 31;          // cols tx*4 .. +3
    const int ty = tid >> 5;          // 0..15, rows ty*4 .. +3
    const int row0 = blockIdx.x * 64;

    // stage z0 = emb[s] * emb[d]
    #pragma unroll
    for (int it = 0; it < 4; ++it) {
        int slot = it * 512 + tid;          // 0..2047
        int r = slot >> 5, c4 = slot & 31;
        int e = row0 + r; if (e >= N_QE) e = N_QE - 1;
        int s = te[e * 2], d = te[e * 2 + 1];
        float4 a = *(const float4*)(emb + (size_t)s * D + c4 * 4);
        float4 b = *(const float4*)(emb + (size_t)d * D + c4 * 4);
        *(float4*)&xs[r][c4 * 4] =
            make_float4(a.x * b.x, a.y * b.y, a.z * b.z, a.w * b.w);
    }

    float acc[4][4];

    #pragma unroll
    for (int layer = 0; layer < 2; ++layer) {
        const float* W = layer ? P2 : P1;
        const float* bb = layer ? pb2 : pb1;
        #pragma unroll
        for (int i = 0; i < 4; ++i)
            #pragma unroll
            for (int c = 0; c < 4; ++c) acc[i][c] = 0.f;

        for (int kc = 0; kc < 4; ++kc) {
            const int kb = kc * 32;
            __syncthreads();
            #pragma unroll
            for (int it = 0; it < 2; ++it) {
                int f = it * 512 + tid;   // 0..1023
                int k = f >> 5, cq = f & 31;
                *(float4*)&ws[k * 128 + cq * 4] =
                    *(const float4*)(W + (size_t)(kb + k) * D + cq * 4);
            }
            __syncthreads();

            #pragma unroll 2
            for (int k4 = 0; k4 < 32; k4 += 4) {
                float4 wv[4];
                #pragma unroll
                for (int kk = 0; kk < 4; ++kk)
                    wv[kk] = *(const float4*)&ws[(k4 + kk) * 128 + tx * 4];
                #pragma unroll
                for (int i = 0; i < 4; ++i) {
                    float4 xv = *(const float4*)&xs[ty * 4 + i][kb + k4];
                    float xk[4] = {xv.x, xv.y, xv.z, xv.w};
                    #pragma unroll
                    for (int kk = 0; kk < 4; ++kk) {
                        acc[i][0] = fmaf(xk[kk], wv[kk].x, acc[i][0]);
                        acc[i][1] = fmaf(xk[kk], wv[kk].y, acc[i][1]);
                        acc[i][2] = fmaf(xk[kk], wv[kk].z, acc[i][2]);
                        acc[i][3] = fmaf(xk[kk], wv[kk].w, acc[i][3]);
                    }
                }
            }
        }
        // bias + relu
        #pragma unroll
        for (int i = 0; i < 4; ++i) {
            acc[i][0] = fmaxf(acc[i][0] + bb[tx * 4 + 0], 0.f);
            acc[i][1] = fmaxf(acc[i][1] + bb[tx * 4 + 1], 0.f);
            acc[i][2] = fmaxf(acc[i][2] + bb[tx * 4 + 2], 0.f);
            acc[i][3] = fmaxf(acc[i][3] + bb[tx * 4 + 3], 0.f);
        }
        if (layer == 0) {
            __syncthreads();
            #pragma unroll
            for (int i = 0; i < 4; ++i)
                *(float4*)&xs[ty * 4 + i][tx * 4] =
                    make_float4(acc[i][0], acc[i][1], acc[i][2], acc[i][3]);
        }
    }

    // epilogue: v = z @ P3 + pb3 (2 cols), reduce over the 32 tx lanes
    float4 p3a = *(const float4*)(P3 + tx * 8);
    float4 p3b = *(const float4*)(P3 + tx * 8 + 4);
    const float q0 = pb3[0], q1 = pb3[1];
    #pragma unroll
    for (int i = 0; i < 4; ++i) {
        float p0 = acc[i][0] * p3a.x + acc[i][1] * p3a.z
                 + acc[i][2] * p3b.x + acc[i][3] * p3b.z;
        float p1 = acc[i][0] * p3a.y + acc[i][1] * p3a.w
                 + acc[i][2] * p3b.y + acc[i][3] * p3b.w;
        #pragma unroll
        for (int o = 1; o < 32; o <<= 1) {
            p0 += __shfl_xor(p0, o, 64);
            p1 += __shfl_xor(p1, o, 64);
        }
        if (tx == 0) {
            int gr = row0 + ty * 4 + i;
            if (gr < N_QE) {
                float v0 = p0 + q0, v1 = p1 + q1;
                float nrm = fmaxf(sqrtf(v0 * v0 + v1 * v1), 1e-12f);
                v0 /= nrm; v1 /= nrm;
                float m = fmaxf(v0, v1);
                float lse = m + logf(expf(v0 - m) + expf(v1 - m));
                out[gr * 2]     = v0 - lse;
                out[gr * 2 + 1] = v1 - lse;
            }
        }
    }
}

extern "C" void kernel_launch(void* const* d_in, const int* in_sizes, int n_in,
                              void* d_out, int out_size, void* d_ws, size_t ws_size,
                              hipStream_t stream)
{
    (void)in_sizes; (void)n_in; (void)out_size; (void)ws_size;
    const float* x   = (const float*)d_in[0];
    const int*   adj = (const int*)d_in[1];
    const int*   te  = (const int*)d_in[2];
    const float* W1  = (const float*)d_in[3];
    const float* b1  = (const float*)d_in[4];
    const float* W2  = (const float*)d_in[5];
    const float* b2  = (const float*)d_in[6];
    const float* W3  = (const float*)d_in[7];
    const float* b3  = (const float*)d_in[8];
    const float* P1  = (const float*)d_in[9];
    const float* pb1 = (const float*)d_in[10];
    const float* P2  = (const float*)d_in[11];
    const float* pb2 = (const float*)d_in[12];
    const float* P3  = (const float*)d_in[13];
    const float* pb3 = (const float*)d_in[14];
    float* out = (float*)d_out;

    char* ws = (char*)d_ws;
    int* cnt  = (int*)(ws + O_CNT);
    int* off  = (int*)(ws + O_OFF);
    int* cur  = (int*)(ws + O_CUR);
    int* bsum = (int*)(ws + O_BS);
    int* srcs = (int*)(ws + O_SRC);
    float* A  = (float*)(ws + O_A);
    float* B  = (float*)(ws + O_B);

    const int* esrc = adj;
    const int* edst = adj + N_EDGES;

    const int SBLK = (N_NODES + 255) / 256;   // 196

    // CSR build (dst-sorted src list), reused by all 3 layers
    hipMemsetAsync(cnt, 0, N_NODES * sizeof(int), stream);
    k_count<<<N_EDGES / 256, 256, 0, stream>>>(edst, cnt);
    k_scan1<<<SBLK, 256, 0, stream>>>(cnt, off, bsum);
    k_scan2<<<1, 256, 0, stream>>>(bsum, SBLK);
    k_scan3<<<SBLK, 256, 0, stream>>>(off, bsum, cur);
    k_scatter<<<N_EDGES / 256, 256, 0, stream>>>(esrc, edst, cur, srcs);

    const int gN = (N_NODES + 63) / 64;   // 782
    const int gQ = (N_QE + 63) / 64;      // 1563

    // GCN trunk (all fp32)
    k_gemm<<<gN, 512, 0, stream>>>(x, W1, A, N_NODES);
    k_agg<true><<<N_NODES / 4, 256, 0, stream>>>(A, off, srcs, b1, B);
    k_gemm<<<gN, 512, 0, stream>>>(B, W2, B, N_NODES);
    k_agg<true><<<N_NODES / 4, 256, 0, stream>>>(B, off, srcs, b2, A);
    k_gemm<<<gN, 512, 0, stream>>>(A, W3, A, N_NODES);
    k_agg<false><<<N_NODES / 4, 256, 0, stream>>>(A, off, srcs, b3, B); // B = emb

    // fused link predictor (512 threads / 64 edges per block)
    k_pred<<<gQ, 512, 0, stream>>>(B, te, P1, pb1, P2, pb2, P3, pb3, out);
}

// Round 2
// 466.454 us; speedup vs baseline: 1.1632x; 1.1632x over previous
//
#include <hip/hip_runtime.h>
#include <math.h>

#define N_NODES 50000
#define N_EDGES 800000
#define N_QE    100000
#define D       128

typedef _Float16 half4 __attribute__((ext_vector_type(4)));

// ---- workspace layout (bytes) ----
static const size_t O_CNT = 0;                        // int[N]
static const size_t O_OFF = 256u * 1024;              // int[N+1]
static const size_t O_CUR = 512u * 1024;              // int[N]
static const size_t O_BS  = 768u * 1024;              // int[256] block sums
static const size_t O_SRC = 1024u * 1024;             // int[E] (3.2 MB)
static const size_t O_A   = 8u << 20;                 // float[N*D] 25.6 MB (agg out / emb)
static const size_t O_H   = O_A + 25600000u;          // _Float16[N*D] 12.8 MB (gemm out)

// ---- CSR build ----
__global__ void k_count(const int* __restrict__ dst, int* __restrict__ cnt) {
    int e = blockIdx.x * 256 + threadIdx.x;
    if (e < N_EDGES) atomicAdd(&cnt[dst[e]], 1);
}

__global__ __launch_bounds__(256)
void k_scan1(const int* __restrict__ cnt, int* __restrict__ off,
             int* __restrict__ bsum) {
    __shared__ int sh[256];
    const int t = threadIdx.x;
    const int i = blockIdx.x * 256 + t;
    int v = (i < N_NODES) ? cnt[i] : 0;
    sh[t] = v;
    __syncthreads();
    #pragma unroll
    for (int o = 1; o < 256; o <<= 1) {
        int u = (t >= o) ? sh[t - o] : 0;
        __syncthreads();
        sh[t] += u;
        __syncthreads();
    }
    if (i < N_NODES) off[i] = sh[t] - v;
    if (t == 255) bsum[blockIdx.x] = sh[255];
}

__global__ __launch_bounds__(256)
void k_scan2(int* __restrict__ bsum, int nblk) {
    __shared__ int sh[256];
    const int t = threadIdx.x;
    int v = (t < nblk) ? bsum[t] : 0;
    sh[t] = v;
    __syncthreads();
    #pragma unroll
    for (int o = 1; o < 256; o <<= 1) {
        int u = (t >= o) ? sh[t - o] : 0;
        __syncthreads();
        sh[t] += u;
        __syncthreads();
    }
    if (t < nblk) bsum[t] = sh[t] - v;
}

__global__ __launch_bounds__(256)
void k_scan3(int* __restrict__ off, const int* __restrict__ bsum,
             int* __restrict__ cur) {
    const int i = blockIdx.x * 256 + threadIdx.x;
    if (i < N_NODES) {
        int o = off[i] + bsum[blockIdx.x];
        off[i] = o;
        cur[i] = o;
    }
    if (i == 0) off[N_NODES] = N_EDGES;
}

__global__ void k_scatter(const int* __restrict__ src, const int* __restrict__ dst,
                          int* __restrict__ cur, int* __restrict__ srcs) {
    int e = blockIdx.x * 256 + threadIdx.x;
    if (e < N_EDGES) {
        int p = atomicAdd(&cur[dst[e]], 1);
        srcs[p] = src[e];
    }
}

// ---- GEMM: Y[rows x 128] = X[rows x 128] @ W[128 x 128], fp32 acc, fp16 out ----
// 512 threads / 64-row tile, 32-k chunks. Output is only ever consumed by the
// gather (k_agg), so fp16 storage halves gather + write traffic; one rounding
// per layer, fp32 accumulation everywhere else.
__global__ __launch_bounds__(512)
void k_gemm(const float* __restrict__ X, const float* __restrict__ W,
            _Float16* __restrict__ Y, int rows)
{
    __shared__ float xs[64][36];
    __shared__ float ws[32 * 128];
    const int tid = threadIdx.x;
    const int tx = tid & 31;
    const int ty = tid >> 5;
    const int row0 = blockIdx.x * 64;
    float acc[4][4] = {};

    for (int kc = 0; kc < 4; ++kc) {
        const int kb = kc * 32;
        __syncthreads();
        {
            int r = tid >> 3, kq = tid & 7;
            int gr = row0 + r; if (gr >= rows) gr = rows - 1;
            float4 v = *(const float4*)(X + (size_t)gr * D + kb + kq * 4);
            *(float4*)&xs[r][kq * 4] = v;
        }
        #pragma unroll
        for (int it = 0; it < 2; ++it) {
            int f = it * 512 + tid;
            int k = f >> 5, cq = f & 31;
            *(float4*)&ws[k * 128 + cq * 4] =
                *(const float4*)(W + (size_t)(kb + k) * D + cq * 4);
        }
        __syncthreads();

        #pragma unroll 2
        for (int k4 = 0; k4 < 32; k4 += 4) {
            float4 wv[4];
            #pragma unroll
            for (int kk = 0; kk < 4; ++kk)
                wv[kk] = *(const float4*)&ws[(k4 + kk) * 128 + tx * 4];
            #pragma unroll
            for (int i = 0; i < 4; ++i) {
                float4 xv = *(const float4*)&xs[ty * 4 + i][k4];
                float xk[4] = {xv.x, xv.y, xv.z, xv.w};
                #pragma unroll
                for (int kk = 0; kk < 4; ++kk) {
                    acc[i][0] = fmaf(xk[kk], wv[kk].x, acc[i][0]);
                    acc[i][1] = fmaf(xk[kk], wv[kk].y, acc[i][1]);
                    acc[i][2] = fmaf(xk[kk], wv[kk].z, acc[i][2]);
                    acc[i][3] = fmaf(xk[kk], wv[kk].w, acc[i][3]);
                }
            }
        }
    }

    #pragma unroll
    for (int i = 0; i < 4; ++i) {
        int gr = row0 + ty * 4 + i;
        if (gr < rows) {
            half4 h;
            h.x = (_Float16)acc[i][0];
            h.y = (_Float16)acc[i][1];
            h.z = (_Float16)acc[i][2];
            h.w = (_Float16)acc[i][3];
            *(half4*)(Y + (size_t)gr * D + tx * 4) = h;
        }
    }
}

// ---- CSR aggregation: fp16 gather, fp32 accumulate. One node per wave. ----
// Lanes 0-31 handle edge j, lanes 32-63 edge j+1; each lane loads 4 cols
// (8 B) -> one 512B wave instruction covers TWO edges. Halves both gather
// bytes (256 B/row vs 512) and VMEM instruction count vs the fp32 design.
// Edge ids via two scalar loads (uniform addr), cross-half shfl_xor combine.
template<bool RELU>
__global__ __launch_bounds__(256)
void k_agg(const _Float16* __restrict__ Hin, const int* __restrict__ off,
           const int* __restrict__ srcs, const float* __restrict__ bias,
           float* __restrict__ Hout)
{
    const int lane = threadIdx.x & 63;
    const int half = lane >> 5;          // which edge of the pair
    const int q    = lane & 31;          // col group: 4q..4q+3
    const int wv   = threadIdx.x >> 6;   // 0..3
    const int n    = blockIdx.x * 4 + wv;
    const int j0 = __builtin_amdgcn_readfirstlane(off[n]);
    const int j1 = __builtin_amdgcn_readfirstlane(off[n + 1]);

    float ax = 0.f, ay = 0.f, az = 0.f, aw = 0.f;
    int j = j0;

    // 8 pairs (16 edges) in flight
    for (; j + 16 <= j1; j += 16) {
        half4 v[8];
        #pragma unroll
        for (int k = 0; k < 8; ++k) {
            int sa = srcs[j + 2 * k];
            int sb = srcs[j + 2 * k + 1];
            int s = half ? sb : sa;
            v[k] = *(const half4*)(Hin + (size_t)s * D + q * 4);
        }
        #pragma unroll
        for (int k = 0; k < 8; ++k) {
            ax += (float)v[k].x; ay += (float)v[k].y;
            az += (float)v[k].z; aw += (float)v[k].w;
        }
    }
    // 2 pairs (4 edges)
    for (; j + 4 <= j1; j += 4) {
        half4 v[2];
        #pragma unroll
        for (int k = 0; k < 2; ++k) {
            int sa = srcs[j + 2 * k];
            int sb = srcs[j + 2 * k + 1];
            int s = half ? sb : sa;
            v[k] = *(const half4*)(Hin + (size_t)s * D + q * 4);
        }
        #pragma unroll
        for (int k = 0; k < 2; ++k) {
            ax += (float)v[k].x; ay += (float)v[k].y;
            az += (float)v[k].z; aw += (float)v[k].w;
        }
    }
    // 1 pair
    for (; j + 2 <= j1; j += 2) {
        int sa = srcs[j];
        int sb = srcs[j + 1];
        int s = half ? sb : sa;
        half4 v = *(const half4*)(Hin + (size_t)s * D + q * 4);
        ax += (float)v.x; ay += (float)v.y; az += (float)v.z; aw += (float)v.w;
    }
    // single tail edge: only half 0 accumulates
    if (j < j1) {
        int s = srcs[j];
        if (!half) {
            half4 v = *(const half4*)(Hin + (size_t)s * D + q * 4);
            ax += (float)v.x; ay += (float)v.y; az += (float)v.z; aw += (float)v.w;
        }
    }

    // combine the two halves (both hold partial sums of the same node/cols)
    ax += __shfl_xor(ax, 32, 64);
    ay += __shfl_xor(ay, 32, 64);
    az += __shfl_xor(az, 32, 64);
    aw += __shfl_xor(aw, 32, 64);

    if (!half) {
        const float4 bb = *(const float4*)(bias + q * 4);
        float4 o = make_float4(ax + bb.x, ay + bb.y, az + bb.z, aw + bb.w);
        if (RELU) {
            o.x = fmaxf(o.x, 0.f); o.y = fmaxf(o.y, 0.f);
            o.z = fmaxf(o.z, 0.f); o.w = fmaxf(o.w, 0.f);
        }
        *(float4*)(Hout + (size_t)n * D + q * 4) = o;
    }
}

// ---- fused link predictor, 512 threads / 64 edges per block (round-0 shape) ----
__global__ __launch_bounds__(512)
void k_pred(const float* __restrict__ emb, const int* __restrict__ te,
            const float* __restrict__ P1, const float* __restrict__ pb1,
            const float* __restrict__ P2, const float* __restrict__ pb2,
            const float* __restrict__ P3, const float* __restrict__ pb3,
            float* __restrict__ out)
{
    __shared__ float xs[64][132];     // full 128-k activations, +4 pad
    __shared__ float ws[64 * 128];    // one 64-k weight chunk
    const int tid = threadIdx.x;      // 0..511
    const int tx = tid & 31;          // cols tx*4 .. +3
    const int ty = tid >> 5;          // 0..15, rows ty*4 .. +3
    const int row0 = blockIdx.x * 64;

    // stage z0 = emb[s] * emb[d]
    #pragma unroll
    for (int it = 0; it < 4; ++it) {
        int slot = it * 512 + tid;          // 0..2047
        int r = slot >> 5, c4 = slot & 31;
        int e = row0 + r; if (e >= N_QE) e = N_QE - 1;
        int s = te[e * 2], d = te[e * 2 + 1];
        float4 a = *(const float4*)(emb + (size_t)s * D + c4 * 4);
        float4 b = *(const float4*)(emb + (size_t)d * D + c4 * 4);
        *(float4*)&xs[r][c4 * 4] =
            make_float4(a.x * b.x, a.y * b.y, a.z * b.z, a.w * b.w);
    }

    float acc[4][4];

    #pragma unroll
    for (int layer = 0; layer < 2; ++layer) {
        const float* W = layer ? P2 : P1;
        const float* bb = layer ? pb2 : pb1;
        #pragma unroll
        for (int i = 0; i < 4; ++i)
            #pragma unroll
            for (int c = 0; c < 4; ++c) acc[i][c] = 0.f;

        for (int kc = 0; kc < 2; ++kc) {
            const int kb = kc * 64;
            __syncthreads();
            #pragma unroll
            for (int it = 0; it < 4; ++it) {
                int f = it * 512 + tid;   // 0..2047
                int k = f >> 5, cq = f & 31;
                *(float4*)&ws[k * 128 + cq * 4] =
                    *(const float4*)(W + (size_t)(kb + k) * D + cq * 4);
            }
            __syncthreads();

            #pragma unroll 2
            for (int k4 = 0; k4 < 64; k4 += 4) {
                float4 wv[4];
                #pragma unroll
                for (int kk = 0; kk < 4; ++kk)
                    wv[kk] = *(const float4*)&ws[(k4 + kk) * 128 + tx * 4];
                #pragma unroll
                for (int i = 0; i < 4; ++i) {
                    float4 xv = *(const float4*)&xs[ty * 4 + i][kb + k4];
                    float xk[4] = {xv.x, xv.y, xv.z, xv.w};
                    #pragma unroll
                    for (int kk = 0; kk < 4; ++kk) {
                        acc[i][0] = fmaf(xk[kk], wv[kk].x, acc[i][0]);
                        acc[i][1] = fmaf(xk[kk], wv[kk].y, acc[i][1]);
                        acc[i][2] = fmaf(xk[kk], wv[kk].z, acc[i][2]);
                        acc[i][3] = fmaf(xk[kk], wv[kk].w, acc[i][3]);
                    }
                }
            }
        }
        // bias + relu
        #pragma unroll
        for (int i = 0; i < 4; ++i) {
            acc[i][0] = fmaxf(acc[i][0] + bb[tx * 4 + 0], 0.f);
            acc[i][1] = fmaxf(acc[i][1] + bb[tx * 4 + 1], 0.f);
            acc[i][2] = fmaxf(acc[i][2] + bb[tx * 4 + 2], 0.f);
            acc[i][3] = fmaxf(acc[i][3] + bb[tx * 4 + 3], 0.f);
        }
        if (layer == 0) {
            __syncthreads();
            #pragma unroll
            for (int i = 0; i < 4; ++i)
                *(float4*)&xs[ty * 4 + i][tx * 4] =
                    make_float4(acc[i][0], acc[i][1], acc[i][2], acc[i][3]);
        }
    }

    // epilogue: v = z @ P3 + pb3 (2 cols), reduce over the 32 tx lanes
    float4 p3a = *(const float4*)(P3 + tx * 8);
    float4 p3b = *(const float4*)(P3 + tx * 8 + 4);
    const float q0 = pb3[0], q1 = pb3[1];
    #pragma unroll
    for (int i = 0; i < 4; ++i) {
        float p0 = acc[i][0] * p3a.x + acc[i][1] * p3a.z
                 + acc[i][2] * p3b.x + acc[i][3] * p3b.z;
        float p1 = acc[i][0] * p3a.y + acc[i][1] * p3a.w
                 + acc[i][2] * p3b.y + acc[i][3] * p3b.w;
        #pragma unroll
        for (int o = 1; o < 32; o <<= 1) {
            p0 += __shfl_xor(p0, o, 64);
            p1 += __shfl_xor(p1, o, 64);
        }
        if (tx == 0) {
            int gr = row0 + ty * 4 + i;
            if (gr < N_QE) {
                float v0 = p0 + q0, v1 = p1 + q1;
                float nrm = fmaxf(sqrtf(v0 * v0 + v1 * v1), 1e-12f);
                v0 /= nrm; v1 /= nrm;
                float m = fmaxf(v0, v1);
                float lse = m + logf(expf(v0 - m) + expf(v1 - m));
                out[gr * 2]     = v0 - lse;
                out[gr * 2 + 1] = v1 - lse;
            }
        }
    }
}

extern "C" void kernel_launch(void* const* d_in, const int* in_sizes, int n_in,
                              void* d_out, int out_size, void* d_ws, size_t ws_size,
                              hipStream_t stream)
{
    (void)in_sizes; (void)n_in; (void)out_size; (void)ws_size;
    const float* x   = (const float*)d_in[0];
    const int*   adj = (const int*)d_in[1];
    const int*   te  = (const int*)d_in[2];
    const float* W1  = (const float*)d_in[3];
    const float* b1  = (const float*)d_in[4];
    const float* W2  = (const float*)d_in[5];
    const float* b2  = (const float*)d_in[6];
    const float* W3  = (const float*)d_in[7];
    const float* b3  = (const float*)d_in[8];
    const float* P1  = (const float*)d_in[9];
    const float* pb1 = (const float*)d_in[10];
    const float* P2  = (const float*)d_in[11];
    const float* pb2 = (const float*)d_in[12];
    const float* P3  = (const float*)d_in[13];
    const float* pb3 = (const float*)d_in[14];
    float* out = (float*)d_out;

    char* ws = (char*)d_ws;
    int* cnt  = (int*)(ws + O_CNT);
    int* off  = (int*)(ws + O_OFF);
    int* cur  = (int*)(ws + O_CUR);
    int* bsum = (int*)(ws + O_BS);
    int* srcs = (int*)(ws + O_SRC);
    float* A      = (float*)(ws + O_A);      // fp32 agg output / emb
    _Float16* H   = (_Float16*)(ws + O_H);   // fp16 gemm output (gather source)

    const int* esrc = adj;
    const int* edst = adj + N_EDGES;

    const int SBLK = (N_NODES + 255) / 256;   // 196

    // CSR build (dst-sorted src list), reused by all 3 layers
    hipMemsetAsync(cnt, 0, N_NODES * sizeof(int), stream);
    k_count<<<N_EDGES / 256, 256, 0, stream>>>(edst, cnt);
    k_scan1<<<SBLK, 256, 0, stream>>>(cnt, off, bsum);
    k_scan2<<<1, 256, 0, stream>>>(bsum, SBLK);
    k_scan3<<<SBLK, 256, 0, stream>>>(off, bsum, cur);
    k_scatter<<<N_EDGES / 256, 256, 0, stream>>>(esrc, edst, cur, srcs);

    const int gN = (N_NODES + 63) / 64;   // 782
    const int gQ = (N_QE + 63) / 64;      // 1563

    // GCN trunk: gemm (fp32 in, fp16 out) -> agg (fp16 gather, fp32 out)
    k_gemm<<<gN, 512, 0, stream>>>(x, W1, H, N_NODES);
    k_agg<true><<<N_NODES / 4, 256, 0, stream>>>(H, off, srcs, b1, A);
    k_gemm<<<gN, 512, 0, stream>>>(A, W2, H, N_NODES);
    k_agg<true><<<N_NODES / 4, 256, 0, stream>>>(H, off, srcs, b2, A);
    k_gemm<<<gN, 512, 0, stream>>>(A, W3, H, N_NODES);
    k_agg<false><<<N_NODES / 4, 256, 0, stream>>>(H, off, srcs, b3, A); // A = emb

    // fused link predictor
    k_pred<<<gQ, 512, 0, stream>>>(A, te, P1, pb1, P2, pb2, P3, pb3, out);
}

// Round 4
// 331.713 us; speedup vs baseline: 1.6357x; 1.4062x over previous
//
#include <hip/hip_runtime.h>
#include <math.h>

#define N_NODES 50000
#define N_EDGES 800000
#define N_QE    100000
#define D       128

typedef _Float16 half4 __attribute__((ext_vector_type(4)));
typedef short    short8 __attribute__((ext_vector_type(8)));
typedef float    f32x4 __attribute__((ext_vector_type(4)));

// fp32 -> bf16 bit pattern, round-to-nearest-even
static __device__ inline short f2bf(float f) {
    unsigned u = __builtin_bit_cast(unsigned, f);
    u += 0x7FFFu + ((u >> 16) & 1u);
    return (short)(u >> 16);
}
// fp32 -> fp16 bit pattern
static __device__ inline short f2h(float f) {
    return (short)__builtin_bit_cast(unsigned short, (_Float16)f);
}

// ---- workspace layout (bytes) ----
static const size_t O_CNT = 0;                        // int[N]
static const size_t O_OFF = 256u * 1024;              // int[N+1]
static const size_t O_CUR = 512u * 1024;              // int[N]
static const size_t O_BS  = 768u * 1024;              // int[256] block sums
static const size_t O_SRC = 1024u * 1024;             // int[E] (3.2 MB)
static const size_t O_A   = 8u << 20;                 // float[N*D] 25.6 MB (agg out / emb)
static const size_t O_H   = O_A + 25600000u;          // _Float16[N*D] 12.8 MB (gemm out)
static const size_t O_T   = O_H + 12800000u;          // short[5*128*128] bf16 W^T

// ---- CSR build ----
__global__ void k_count(const int* __restrict__ dst, int* __restrict__ cnt) {
    int e = blockIdx.x * 256 + threadIdx.x;
    if (e < N_EDGES) atomicAdd(&cnt[dst[e]], 1);
}

__global__ __launch_bounds__(256)
void k_scan1(const int* __restrict__ cnt, int* __restrict__ off,
             int* __restrict__ bsum) {
    __shared__ int sh[256];
    const int t = threadIdx.x;
    const int i = blockIdx.x * 256 + t;
    int v = (i < N_NODES) ? cnt[i] : 0;
    sh[t] = v;
    __syncthreads();
    #pragma unroll
    for (int o = 1; o < 256; o <<= 1) {
        int u = (t >= o) ? sh[t - o] : 0;
        __syncthreads();
        sh[t] += u;
        __syncthreads();
    }
    if (i < N_NODES) off[i] = sh[t] - v;
    if (t == 255) bsum[blockIdx.x] = sh[255];
}

__global__ __launch_bounds__(256)
void k_scan2(int* __restrict__ bsum, int nblk) {
    __shared__ int sh[256];
    const int t = threadIdx.x;
    int v = (t < nblk) ? bsum[t] : 0;
    sh[t] = v;
    __syncthreads();
    #pragma unroll
    for (int o = 1; o < 256; o <<= 1) {
        int u = (t >= o) ? sh[t - o] : 0;
        __syncthreads();
        sh[t] += u;
        __syncthreads();
    }
    if (t < nblk) bsum[t] = sh[t] - v;
}

__global__ __launch_bounds__(256)
void k_scan3(int* __restrict__ off, const int* __restrict__ bsum,
             int* __restrict__ cur) {
    const int i = blockIdx.x * 256 + threadIdx.x;
    if (i < N_NODES) {
        int o = off[i] + bsum[blockIdx.x];
        off[i] = o;
        cur[i] = o;
    }
    if (i == 0) off[N_NODES] = N_EDGES;
}

__global__ void k_scatter(const int* __restrict__ src, const int* __restrict__ dst,
                          int* __restrict__ cur, int* __restrict__ srcs) {
    int e = blockIdx.x * 256 + threadIdx.x;
    if (e < N_EDGES) {
        int p = atomicAdd(&cur[dst[e]], 1);
        srcs[p] = src[e];
    }
}

// ---- weight transpose + bf16 cast: T[m][c][k] = bf16( W_m[k][c] ) ----
__global__ __launch_bounds__(256)
void k_t16all(const float* __restrict__ W1, const float* __restrict__ W2,
              const float* __restrict__ W3, const float* __restrict__ Q1,
              const float* __restrict__ Q2, short* __restrict__ T)
{
    int m = blockIdx.x >> 6;             // 0..4
    const float* S = (m == 0) ? W1 : (m == 1) ? W2 : (m == 2) ? W3
                   : (m == 3) ? Q1 : Q2;
    short* Dp = T + m * 16384;
    int idx = (blockIdx.x & 63) * 256 + threadIdx.x;   // 0..16383
    int c = idx & 127, k = idx >> 7;
    Dp[c * 128 + k] = f2bf(S[k * 128 + c]);
}

// ============================================================================
// MFMA 16x16x32_bf16 (HW-verified instruction, learn_hip m89/m91/m97):
//   A (16x32): lane l holds A[l&15][8*(l>>4)+j], j=0..7   (short8 of bf16)
//   B (32x16): lane l holds B[8*(l>>4)+j][l&15]
//   C/D:       lane l reg i = D[(l>>4)*4 + i][l&15]       (m89-verified)
// xs[64 rows][16 slots of 8 bf16]; slot' = slot ^ (row&7) swizzle keeps
// same-slot/different-row fragment reads conflict-free.
// ============================================================================

// ---- trunk GEMM: H16[rows x 128] = fp16( X @ W ) via bf16 MFMA ----
__global__ __launch_bounds__(256)
void k_mm(const float* __restrict__ X, const short* __restrict__ WT,
          _Float16* __restrict__ Y, int rows)
{
    __shared__ __align__(16) short xs[64 * 128];
    const int tid = threadIdx.x;
    const int l   = tid & 63;
    const int w   = tid >> 6;
    const int g   = l >> 4;
    const int l15 = l & 15;
    const int row0 = blockIdx.x * 64;

    // stage X -> bf16 LDS (swizzled)
    {
        int r = tid >> 2;
        int gr = row0 + r; if (gr >= rows) gr = rows - 1;
        const float* src = X + (size_t)gr * D;
        #pragma unroll
        for (int it = 0; it < 4; ++it) {
            int s = (tid & 3) + it * 4;
            float4 v0 = *(const float4*)(src + s * 8);
            float4 v1 = *(const float4*)(src + s * 8 + 4);
            short8 h;
            h[0] = f2bf(v0.x); h[1] = f2bf(v0.y);
            h[2] = f2bf(v0.z); h[3] = f2bf(v0.w);
            h[4] = f2bf(v1.x); h[5] = f2bf(v1.y);
            h[6] = f2bf(v1.z); h[7] = f2bf(v1.w);
            *(short8*)&xs[r * 128 + ((s ^ (r & 7)) * 8)] = h;
        }
    }

    // W fragments for this wave's 2 col-tiles (registers)
    short8 wf[2][4];
    #pragma unroll
    for (int tt = 0; tt < 2; ++tt) {
        int c = w * 32 + tt * 16 + l15;
        #pragma unroll
        for (int s = 0; s < 4; ++s)
            wf[tt][s] = *(const short8*)(WT + (size_t)c * 128 + s * 32 + g * 8);
    }

    __syncthreads();

    f32x4 acc[4][2];
    #pragma unroll
    for (int rt = 0; rt < 4; ++rt)
        #pragma unroll
        for (int tt = 0; tt < 2; ++tt)
            acc[rt][tt] = (f32x4){0.f, 0.f, 0.f, 0.f};

    #pragma unroll
    for (int rt = 0; rt < 4; ++rt) {
        const int r = rt * 16 + l15;
        short8 a[4];
        #pragma unroll
        for (int s = 0; s < 4; ++s) {
            int slot = (4 * s + g) ^ (r & 7);
            a[s] = *(const short8*)&xs[r * 128 + slot * 8];
        }
        #pragma unroll
        for (int tt = 0; tt < 2; ++tt)
            #pragma unroll
            for (int s = 0; s < 4; ++s)
                acc[rt][tt] = __builtin_amdgcn_mfma_f32_16x16x32_bf16(
                    a[s], wf[tt][s], acc[rt][tt], 0, 0, 0);
    }

    __syncthreads();   // all A-frag reads done before overwrite

    // write C frags back to LDS as fp16 bit patterns (swizzled), then store
    #pragma unroll
    for (int rt = 0; rt < 4; ++rt)
        #pragma unroll
        for (int tt = 0; tt < 2; ++tt) {
            int c = w * 32 + tt * 16 + l15;
            #pragma unroll
            for (int i = 0; i < 4; ++i) {
                int row = rt * 16 + g * 4 + i;
                int slot = (c >> 3) ^ (row & 7);
                xs[row * 128 + slot * 8 + (c & 7)] = f2h(acc[rt][tt][i]);
            }
        }
    __syncthreads();

    {
        int r = tid >> 2;
        int gr = row0 + r;
        if (gr < rows) {
            short* dstp = (short*)(Y + (size_t)gr * D);
            #pragma unroll
            for (int it = 0; it < 4; ++it) {
                int s = (tid & 3) + it * 4;
                *(short8*)(dstp + s * 8) =
                    *(const short8*)&xs[r * 128 + ((s ^ (r & 7)) * 8)];
            }
        }
    }
}

// ---- CSR aggregation: fp16 gather, fp32 accumulate. One node per wave. ----
template<bool RELU>
__global__ __launch_bounds__(256)
void k_agg(const _Float16* __restrict__ Hin, const int* __restrict__ off,
           const int* __restrict__ srcs, const float* __restrict__ bias,
           float* __restrict__ Hout)
{
    const int lane = threadIdx.x & 63;
    const int half = lane >> 5;
    const int q    = lane & 31;
    const int wv   = threadIdx.x >> 6;
    const int n    = blockIdx.x * 4 + wv;
    const int j0 = __builtin_amdgcn_readfirstlane(off[n]);
    const int j1 = __builtin_amdgcn_readfirstlane(off[n + 1]);

    float ax = 0.f, ay = 0.f, az = 0.f, aw = 0.f;
    int j = j0;

    for (; j + 16 <= j1; j += 16) {
        half4 v[8];
        #pragma unroll
        for (int k = 0; k < 8; ++k) {
            int sa = srcs[j + 2 * k];
            int sb = srcs[j + 2 * k + 1];
            int s = half ? sb : sa;
            v[k] = *(const half4*)(Hin + (size_t)s * D + q * 4);
        }
        #pragma unroll
        for (int k = 0; k < 8; ++k) {
            ax += (float)v[k].x; ay += (float)v[k].y;
            az += (float)v[k].z; aw += (float)v[k].w;
        }
    }
    for (; j + 4 <= j1; j += 4) {
        half4 v[2];
        #pragma unroll
        for (int k = 0; k < 2; ++k) {
            int sa = srcs[j + 2 * k];
            int sb = srcs[j + 2 * k + 1];
            int s = half ? sb : sa;
            v[k] = *(const half4*)(Hin + (size_t)s * D + q * 4);
        }
        #pragma unroll
        for (int k = 0; k < 2; ++k) {
            ax += (float)v[k].x; ay += (float)v[k].y;
            az += (float)v[k].z; aw += (float)v[k].w;
        }
    }
    for (; j + 2 <= j1; j += 2) {
        int sa = srcs[j];
        int sb = srcs[j + 1];
        int s = half ? sb : sa;
        half4 v = *(const half4*)(Hin + (size_t)s * D + q * 4);
        ax += (float)v.x; ay += (float)v.y; az += (float)v.z; aw += (float)v.w;
    }
    if (j < j1) {
        int s = srcs[j];
        if (!half) {
            half4 v = *(const half4*)(Hin + (size_t)s * D + q * 4);
            ax += (float)v.x; ay += (float)v.y; az += (float)v.z; aw += (float)v.w;
        }
    }

    ax += __shfl_xor(ax, 32, 64);
    ay += __shfl_xor(ay, 32, 64);
    az += __shfl_xor(az, 32, 64);
    aw += __shfl_xor(aw, 32, 64);

    if (!half) {
        const float4 bb = *(const float4*)(bias + q * 4);
        float4 o = make_float4(ax + bb.x, ay + bb.y, az + bb.z, aw + bb.w);
        if (RELU) {
            o.x = fmaxf(o.x, 0.f); o.y = fmaxf(o.y, 0.f);
            o.z = fmaxf(o.z, 0.f); o.w = fmaxf(o.w, 0.f);
        }
        *(float4*)(Hout + (size_t)n * D + q * 4) = o;
    }
}

// ---- MFMA link predictor: 256 thr / 64 edges per block ----
__global__ __launch_bounds__(256)
void k_predm(const float* __restrict__ emb, const int* __restrict__ te,
             const short* __restrict__ P1T, const float* __restrict__ pb1,
             const short* __restrict__ P2T, const float* __restrict__ pb2,
             const float* __restrict__ P3, const float* __restrict__ pb3,
             float* __restrict__ out)
{
    __shared__ __align__(16) short xs[64 * 128];
    __shared__ float red[64][8];
    const int tid = threadIdx.x;
    const int l   = tid & 63;
    const int w   = tid >> 6;
    const int g   = l >> 4;
    const int l15 = l & 15;
    const int row0 = blockIdx.x * 64;

    // stage z0 = emb[s] * emb[d] -> bf16 LDS (swizzled)
    {
        int r = tid >> 2;
        int e = row0 + r; if (e >= N_QE) e = N_QE - 1;
        const int2 ee = *(const int2*)(te + 2 * e);
        const float* sp = emb + (size_t)ee.x * D;
        const float* dp = emb + (size_t)ee.y * D;
        #pragma unroll
        for (int it = 0; it < 4; ++it) {
            int s = (tid & 3) + it * 4;
            float4 a0 = *(const float4*)(sp + s * 8);
            float4 a1 = *(const float4*)(sp + s * 8 + 4);
            float4 b0 = *(const float4*)(dp + s * 8);
            float4 b1 = *(const float4*)(dp + s * 8 + 4);
            short8 h;
            h[0] = f2bf(a0.x * b0.x); h[1] = f2bf(a0.y * b0.y);
            h[2] = f2bf(a0.z * b0.z); h[3] = f2bf(a0.w * b0.w);
            h[4] = f2bf(a1.x * b1.x); h[5] = f2bf(a1.y * b1.y);
            h[6] = f2bf(a1.z * b1.z); h[7] = f2bf(a1.w * b1.w);
            *(short8*)&xs[r * 128 + ((s ^ (r & 7)) * 8)] = h;
        }
    }
    __syncthreads();

    f32x4 acc[4][2];

    // ---------------- layer 1 ----------------
    {
        short8 wf[2][4];
        #pragma unroll
        for (int tt = 0; tt < 2; ++tt) {
            int c = w * 32 + tt * 16 + l15;
            #pragma unroll
            for (int s = 0; s < 4; ++s)
                wf[tt][s] = *(const short8*)(P1T + (size_t)c * 128 + s * 32 + g * 8);
        }
        #pragma unroll
        for (int rt = 0; rt < 4; ++rt)
            #pragma unroll
            for (int tt = 0; tt < 2; ++tt)
                acc[rt][tt] = (f32x4){0.f, 0.f, 0.f, 0.f};

        #pragma unroll
        for (int rt = 0; rt < 4; ++rt) {
            const int r = rt * 16 + l15;
            short8 a[4];
            #pragma unroll
            for (int s = 0; s < 4; ++s) {
                int slot = (4 * s + g) ^ (r & 7);
                a[s] = *(const short8*)&xs[r * 128 + slot * 8];
            }
            #pragma unroll
            for (int tt = 0; tt < 2; ++tt)
                #pragma unroll
                for (int s = 0; s < 4; ++s)
                    acc[rt][tt] = __builtin_amdgcn_mfma_f32_16x16x32_bf16(
                        a[s], wf[tt][s], acc[rt][tt], 0, 0, 0);
        }

        float bv[2];
        #pragma unroll
        for (int tt = 0; tt < 2; ++tt) bv[tt] = pb1[w * 32 + tt * 16 + l15];

        __syncthreads();   // reads done before overwrite

        #pragma unroll
        for (int rt = 0; rt < 4; ++rt)
            #pragma unroll
            for (int tt = 0; tt < 2; ++tt) {
                int c = w * 32 + tt * 16 + l15;
                #pragma unroll
                for (int i = 0; i < 4; ++i) {
                    float v = fmaxf(acc[rt][tt][i] + bv[tt], 0.f);
                    int row = rt * 16 + g * 4 + i;
                    int slot = (c >> 3) ^ (row & 7);
                    xs[row * 128 + slot * 8 + (c & 7)] = f2bf(v);
                }
            }
        __syncthreads();
    }

    // ---------------- layer 2 (acc kept for epilogue) ----------------
    {
        short8 wf[2][4];
        #pragma unroll
        for (int tt = 0; tt < 2; ++tt) {
            int c = w * 32 + tt * 16 + l15;
            #pragma unroll
            for (int s = 0; s < 4; ++s)
                wf[tt][s] = *(const short8*)(P2T + (size_t)c * 128 + s * 32 + g * 8);
        }
        #pragma unroll
        for (int rt = 0; rt < 4; ++rt)
            #pragma unroll
            for (int tt = 0; tt < 2; ++tt)
                acc[rt][tt] = (f32x4){0.f, 0.f, 0.f, 0.f};

        #pragma unroll
        for (int rt = 0; rt < 4; ++rt) {
            const int r = rt * 16 + l15;
            short8 a[4];
            #pragma unroll
            for (int s = 0; s < 4; ++s) {
                int slot = (4 * s + g) ^ (r & 7);
                a[s] = *(const short8*)&xs[r * 128 + slot * 8];
            }
            #pragma unroll
            for (int tt = 0; tt < 2; ++tt)
                #pragma unroll
                for (int s = 0; s < 4; ++s)
                    acc[rt][tt] = __builtin_amdgcn_mfma_f32_16x16x32_bf16(
                        a[s], wf[tt][s], acc[rt][tt], 0, 0, 0);
        }
    }

    // bias + relu on layer-2 acc, then P3 partials + reduce
    {
        float bv[2];
        float2 p3v[2];
        #pragma unroll
        for (int tt = 0; tt < 2; ++tt) {
            int c = w * 32 + tt * 16 + l15;
            bv[tt] = pb2[c];
            p3v[tt] = *(const float2*)(P3 + c * 2);
        }
        #pragma unroll
        for (int rt = 0; rt < 4; ++rt)
            #pragma unroll
            for (int i = 0; i < 4; ++i) {
                float z0 = fmaxf(acc[rt][0][i] + bv[0], 0.f);
                float z1 = fmaxf(acc[rt][1][i] + bv[1], 0.f);
                float p0 = z0 * p3v[0].x + z1 * p3v[1].x;
                float p1 = z0 * p3v[0].y + z1 * p3v[1].y;
                #pragma unroll
                for (int o = 1; o < 16; o <<= 1) {
                    p0 += __shfl_xor(p0, o, 64);
                    p1 += __shfl_xor(p1, o, 64);
                }
                if (l15 == 0) {
                    int row = rt * 16 + g * 4 + i;
                    red[row][w * 2]     = p0;
                    red[row][w * 2 + 1] = p1;
                }
            }
    }
    __syncthreads();

    if (tid < 64) {
        int gr = row0 + tid;
        if (gr < N_QE) {
            float p0 = red[tid][0] + red[tid][2] + red[tid][4] + red[tid][6] + pb3[0];
            float p1 = red[tid][1] + red[tid][3] + red[tid][5] + red[tid][7] + pb3[1];
            float nrm = fmaxf(sqrtf(p0 * p0 + p1 * p1), 1e-12f);
            p0 /= nrm; p1 /= nrm;
            float m = fmaxf(p0, p1);
            float lse = m + logf(expf(p0 - m) + expf(p1 - m));
            out[gr * 2]     = p0 - lse;
            out[gr * 2 + 1] = p1 - lse;
        }
    }
}

extern "C" void kernel_launch(void* const* d_in, const int* in_sizes, int n_in,
                              void* d_out, int out_size, void* d_ws, size_t ws_size,
                              hipStream_t stream)
{
    (void)in_sizes; (void)n_in; (void)out_size; (void)ws_size;
    const float* x   = (const float*)d_in[0];
    const int*   adj = (const int*)d_in[1];
    const int*   te  = (const int*)d_in[2];
    const float* W1  = (const float*)d_in[3];
    const float* b1  = (const float*)d_in[4];
    const float* W2  = (const float*)d_in[5];
    const float* b2  = (const float*)d_in[6];
    const float* W3  = (const float*)d_in[7];
    const float* b3  = (const float*)d_in[8];
    const float* P1  = (const float*)d_in[9];
    const float* pb1 = (const float*)d_in[10];
    const float* P2  = (const float*)d_in[11];
    const float* pb2 = (const float*)d_in[12];
    const float* P3  = (const float*)d_in[13];
    const float* pb3 = (const float*)d_in[14];
    float* out = (float*)d_out;

    char* ws = (char*)d_ws;
    int* cnt  = (int*)(ws + O_CNT);
    int* off  = (int*)(ws + O_OFF);
    int* cur  = (int*)(ws + O_CUR);
    int* bsum = (int*)(ws + O_BS);
    int* srcs = (int*)(ws + O_SRC);
    float*    A = (float*)(ws + O_A);       // fp32 agg output / emb
    _Float16* H = (_Float16*)(ws + O_H);    // fp16 gemm output (gather source)
    short*    T = (short*)(ws + O_T);       // bf16 transposed weights (5x 128x128)

    const int* esrc = adj;
    const int* edst = adj + N_EDGES;

    const int SBLK = (N_NODES + 255) / 256;   // 196

    // transposed bf16 weights (all 5 dense layers)
    k_t16all<<<320, 256, 0, stream>>>(W1, W2, W3, P1, P2, T);

    // CSR build (dst-sorted src list), reused by all 3 layers
    hipMemsetAsync(cnt, 0, N_NODES * sizeof(int), stream);
    k_count<<<N_EDGES / 256, 256, 0, stream>>>(edst, cnt);
    k_scan1<<<SBLK, 256, 0, stream>>>(cnt, off, bsum);
    k_scan2<<<1, 256, 0, stream>>>(bsum, SBLK);
    k_scan3<<<SBLK, 256, 0, stream>>>(off, bsum, cur);
    k_scatter<<<N_EDGES / 256, 256, 0, stream>>>(esrc, edst, cur, srcs);

    const int gN = (N_NODES + 63) / 64;   // 782
    const int gQ = (N_QE + 63) / 64;      // 1563

    // GCN trunk: bf16-MFMA gemm (fp32 in, fp16 out) -> agg (fp16 gather)
    k_mm<<<gN, 256, 0, stream>>>(x, T,             H, N_NODES);
    k_agg<true><<<N_NODES / 4, 256, 0, stream>>>(H, off, srcs, b1, A);
    k_mm<<<gN, 256, 0, stream>>>(A, T + 16384,     H, N_NODES);
    k_agg<true><<<N_NODES / 4, 256, 0, stream>>>(H, off, srcs, b2, A);
    k_mm<<<gN, 256, 0, stream>>>(A, T + 2 * 16384, H, N_NODES);
    k_agg<false><<<N_NODES / 4, 256, 0, stream>>>(H, off, srcs, b3, A); // A = emb

    // bf16-MFMA link predictor
    k_predm<<<gQ, 256, 0, stream>>>(A, te, T + 3 * 16384, pb1,
                                    T + 4 * 16384, pb2, P3, pb3, out);
}